// Round 19
// baseline (226.457 us; speedup 1.0000x reference)
//
#include <hip/hip_runtime.h>
#include <hip/hip_bf16.h>
#include <stdint.h>
#include <math.h>

#define XLEN   262144
#define NT     513
#define NTP    528               // padded frames per batch (8*528 = 4224)
#define NB     8
#define NCOL   (NB * NTP)        // 4224 fused columns
#define PROW   256               // computed k rows in GEMM: 0..255 (k=256 via T)
#define KQ     512               // quarter transform length (radix-4)
#define NK     1088              // fallback path: direct rows
#define NFFT   2048
#define OUTKT  (2048 * NT)
#define WSTR   ((size_t)PROW * KQ)   // 131,072 shorts per weight mat
#define FSTR   ((size_t)NCOL * KQ)   // 2,162,688 shorts per frame mat
#define PSTR   ((size_t)PROW * NCOL) // 1,081,344 elements per partial (bf16)
#define NWG4   528                   // GEMM grid: 4 k-tiles x 33 j-tiles x 4 sides
#define NGRP   132                   // dependency groups: 4 ktiles x 33 jtiles

typedef __attribute__((ext_vector_type(8))) short short8;
typedef __attribute__((ext_vector_type(4))) short short4v;
typedef __attribute__((ext_vector_type(2))) short short2v;
typedef __attribute__((ext_vector_type(4))) float f32x4;

__device__ __forceinline__ short cvt_bf16(float f) {
  return __builtin_bit_cast(short, (__bf16)f);
}

__device__ __forceinline__ f32x4 bf4_to_f32(short4v v) {
  f32x4 o;
#pragma unroll
  for (int e = 0; e < 4; ++e) {
    uint32_t u = ((uint32_t)(uint16_t)v[e]) << 16;
    o[e] = __builtin_bit_cast(float, u);
  }
  return o;
}

__device__ __forceinline__ void gload16(const short* g, const short* l) {
  __builtin_amdgcn_global_load_lds(
      (const __attribute__((address_space(1))) void*)g,
      (__attribute__((address_space(3))) void*)l, 16, 0, 0);
}

// ---- shared combine item (R18-proven butterfly + mirrors) ----
// k in [0,255]: C/S from bf16 partials; k==256: synthesized from Tbuf (fp32).
__device__ __forceinline__ void combine_item(
    int k, int jq, const short* __restrict__ pC4, const short* __restrict__ pS4,
    const float* __restrict__ Tbuf,
    float* __restrict__ outR, float* __restrict__ outI) {
  if (jq >= NCOL / 4) return;
  const int j = jq * 4;
  const int b = j / NTP;
  const int t = j - b * NTP;                       // NTP%4==0 -> same b for all 4
  const float RT2 = 0.70710678118654752f;
  f32x4 C[4], S[4];
  if (k == 256) {
    const float ct8[4] = {1.f, RT2, 0.f, -RT2};    // cos(pi r/4)
    const float st8[4] = {0.f, RT2, 1.f, RT2};     // sin(pi r/4)
#pragma unroll
    for (int e = 0; e < 4; ++e) {
      f32x4 tj = *(const f32x4*)&Tbuf[(size_t)(j + e) * 4];
#pragma unroll
      for (int r = 0; r < 4; ++r) {
        C[r][e] = ct8[r] * tj[r];
        S[r][e] = st8[r] * tj[r];
      }
    }
  } else {
    const size_t pb = (size_t)k * NCOL + j;
#pragma unroll
    for (int r = 0; r < 4; ++r) {
      C[r] = bf4_to_f32(*(const short4v*)&pC4[r * PSTR + pb]);
      S[r] = bf4_to_f32(*(const short4v*)&pS4[r * PSTR + pb]);
    }
  }
  const f32x4 CA = C[0] + C[2], CB = C[1] + C[3];
  const f32x4 CmA = C[0] - C[2], CmB = C[1] - C[3];
  const f32x4 SA = S[0] + S[2], SB = S[1] + S[3];
  const f32x4 SmA = S[0] - S[2], SmB = S[1] - S[3];

  f32x4 Cw[4], Sw[4];
  Cw[0] = CA + CB;   Sw[0] = SA + SB;    // row k
  Cw[1] = CmA - SmB; Sw[1] = SmA + CmB;  // row 512+k
  Cw[2] = CA - CB;   Sw[2] = SA - SB;    // row 1024+k
  Cw[3] = CmA + SmB; Sw[3] = SmA - CmB;  // row 1536+k

  const size_t ob = (size_t)b * OUTKT + t;
  const bool mir = (k >= 1) && (k <= 255);
#pragma unroll
  for (int jj = 0; jj < 4; ++jj) {
    const int rowD = 512 * jj + k;
    float* rD = outR + ob + (size_t)rowD * NT;
    float* iD = outI + ob + (size_t)rowD * NT;
    const int rowM = 512 * (4 - jj) - k;  // 2048-d
    float* rM = outR + ob + (size_t)rowM * NT;
    float* iM = outI + ob + (size_t)rowM * NT;
#pragma unroll
    for (int e = 0; e < 4; ++e) {
      if (t + e < NT) {
        rD[e] = Cw[jj][e];
        iD[e] = -Sw[jj][e];
        if (mir) { rM[e] = Cw[jj][e]; iM[e] = Sw[jj][e]; }
      }
    }
  }
}

// ==================== radix-4 split path ====================

// ---- fused prep (R18-proven): weight rows 0..255 + frame split + T reduction.
// Block 0 additionally zeroes the NGRP group counters (every launch/replay).
__global__ __launch_bounds__(256) void conv_prep4(
    const float* __restrict__ x,
    const float* __restrict__ wsin, const float* __restrict__ wcos,
    short* __restrict__ wc4, short* __restrict__ ws4,
    short* __restrict__ fr4, float* __restrict__ Tbuf,
    int* __restrict__ cnt) {
  const int tid = threadIdx.x;
  const int n0 = tid * 8;
  const int m0 = n0 >> 2;
  if (blockIdx.x == 0 && tid < NGRP) cnt[tid] = 0;
  if (blockIdx.x < PROW) {
    const int row = blockIdx.x;           // 0..255, all valid
    short2v c[4], s[4];
    const float* pc = wcos + (size_t)row * NFFT + n0;
    const float* ps = wsin + (size_t)row * NFFT + n0;
    f32x4 c0 = *(const f32x4*)pc, c1 = *(const f32x4*)(pc + 4);
    f32x4 s0 = *(const f32x4*)ps, s1 = *(const f32x4*)(ps + 4);
#pragma unroll
    for (int r = 0; r < 4; ++r) {
      c[r][0] = cvt_bf16(c0[r]); c[r][1] = cvt_bf16(c1[r]);
      s[r][0] = cvt_bf16(s0[r]); s[r][1] = cvt_bf16(s1[r]);
    }
    const size_t o = (size_t)row * KQ + m0;
#pragma unroll
    for (int r = 0; r < 4; ++r) {
      *(short2v*)&wc4[r * WSTR + o] = c[r];
      *(short2v*)&ws4[r * WSTR + o] = s[r];
    }
  } else {
    const int j = blockIdx.x - PROW;      // 0..4223
    const int b = j / NTP;
    const int t = j - b * NTP;
    short2v v[4];
    float con[4] = {0.f, 0.f, 0.f, 0.f};
    if (t < NT) {
      const float* xb = x + (size_t)b * XLEN;
      const int q0 = t * 512 + n0 - 1024;
      float f[8];
      if (q0 >= 0 && q0 + 7 < XLEN) {
        *(f32x4*)(f)     = *(const f32x4*)(xb + q0);
        *(f32x4*)(f + 4) = *(const f32x4*)(xb + q0 + 4);
      } else {
#pragma unroll
        for (int e = 0; e < 8; ++e) {
          int mm = q0 + e;
          mm = (mm < 0) ? -mm : mm;
          mm = (mm >= XLEN) ? (2 * XLEN - 2 - mm) : mm;
          f[e] = xb[mm];
        }
      }
      float wn[8];
#pragma unroll
      for (int e = 0; e < 8; ++e)
        wn[e] = 0.5f - 0.5f * cosf((float)(M_PI / 1024.0) * (float)(n0 + e));
#pragma unroll
      for (int r = 0; r < 4; ++r) {
        v[r][0] = cvt_bf16(f[r]); v[r][1] = cvt_bf16(f[4 + r]);
        con[r] = wn[r] * f[r] - wn[4 + r] * f[4 + r];  // m even (+), m odd (-)
      }
    } else {
#pragma unroll
      for (int r = 0; r < 4; ++r) { v[r][0] = 0; v[r][1] = 0; }
    }
#pragma unroll
    for (int r = 0; r < 4; ++r)
      *(short2v*)&fr4[r * FSTR + (size_t)j * KQ + m0] = v[r];

    // block reduction of con[4] -> Tbuf[j][0..3]
    const int lane = tid & 63;
    const int wid  = tid >> 6;
#pragma unroll
    for (int r = 0; r < 4; ++r)
#pragma unroll
      for (int off = 32; off >= 1; off >>= 1)
        con[r] += __shfl_down(con[r], off);
    __shared__ float tred[4][4];
    if (lane == 0) {
#pragma unroll
      for (int r = 0; r < 4; ++r) tred[wid][r] = con[r];
    }
    __syncthreads();
    if (tid < 4)
      Tbuf[(size_t)j * 4 + tid] =
          tred[0][tid] + tred[1][tid] + tred[2][tid] + tred[3][tid];
  }
}

// ---- fused GEMM + last-arriver combine ----
// GEMM: R16-proven structure (BM=64, BN=128, BK=64; 4 waves 2x2; 8 ds_read :
// 16 MFMA per substep; 32 KiB LDS; (row&7) swizzle both sides; bf16 partials).
// Tail: group = (ktile, jtile); 4 side-blocks per group. Release fence +
// atomicAdd; the 4th arriver acquire-fences and combines its 64k x 128j
// region (2048 items; ktile 3 also emits the closed-form k=256 rows).
__global__ __launch_bounds__(256, 3) void dft_gemm_split4(
    const short* __restrict__ wc4, const short* __restrict__ ws4,
    const short* __restrict__ fr4,
    short* __restrict__ pC4, short* __restrict__ pS4,
    const float* __restrict__ Tbuf, int* __restrict__ cnt,
    float* __restrict__ outR, float* __restrict__ outI) {
  __shared__ short lds[16384];  // 32 KiB

  const int tid  = threadIdx.x;
  const int lane = tid & 63;
  const int wid  = tid >> 6;

  // XCD swizzle: nwg = 528 = 8 x 66 (exact) -> wg = xcd*66 + idx, bijective.
  const int o   = blockIdx.x;
  const int xcd = o & 7;
  const int wg  = xcd * 66 + (o >> 3);
  const int side = wg / 132;        // residue r = 0..3 (132 wg per side)
  const int w    = wg - side * 132;
  const int kt   = w % 4;
  const int k0   = kt * 64;         // 4 k-tiles: rows 0..255
  const int j0   = (w / 4) * 128;
  const int grp  = kt * 33 + (w / 4);

  const short* Ac = wc4 + side * WSTR;
  const short* As = ws4 + side * WSTR;
  const short* Bf = fr4 + side * FSTR;
  short* pC = pC4 + side * PSTR;
  short* pS = pS4 + side * PSTR;

  const int wrow = (wid >> 1) * 32;
  const int wcol = (wid & 1) * 64;

  f32x4 accC[2][4], accS[2][4];
#pragma unroll
  for (int m = 0; m < 2; ++m)
#pragma unroll
    for (int n = 0; n < 4; ++n) { accC[m][n] = (f32x4)0.0f; accS[m][n] = (f32x4)0.0f; }

  const int fr_r = lane & 15;
  const int srow = lane >> 3;
  const int scol = ((lane & 7) ^ srow) * 8;

  // buffer = 32 chunks of (8 rows x 64 shorts); 8 per wave
  auto stage = [&](int n0) {
#pragma unroll
    for (int i2 = 0; i2 < 8; ++i2) {
      const int q = wid * 8 + i2;  // wave-uniform
      const short* src;
      int dst;
      if (q < 8) {
        src = Ac + (size_t)(k0 + q * 8 + srow) * KQ + n0 + scol;
        dst = q * 512;
      } else if (q < 16) {
        src = As + (size_t)(k0 + (q - 8) * 8 + srow) * KQ + n0 + scol;
        dst = 4096 + (q - 8) * 512;
      } else {
        src = Bf + (size_t)(j0 + (q - 16) * 8 + srow) * KQ + n0 + scol;
        dst = 8192 + (q - 16) * 512;
      }
      gload16(src, &lds[dst]);
    }
  };

  for (int ts = 0; ts < 8; ++ts) {
    if (ts) __syncthreads();
    stage(ts * 64);
    __syncthreads();
#pragma unroll
    for (int ks = 0; ks < 2; ++ks) {
      const int cc = ks * 4 + (lane >> 4);
      short8 aC[2], aS[2], bF[4];
#pragma unroll
      for (int m = 0; m < 2; ++m) {
        const int r = wrow + m * 16 + fr_r;
        const int off = (r << 6) + ((cc ^ (r & 7)) << 3);
        aC[m] = *(const short8*)&lds[off];
        aS[m] = *(const short8*)&lds[4096 + off];
      }
#pragma unroll
      for (int n = 0; n < 4; ++n) {
        const int r = wcol + n * 16 + fr_r;
        const int off = (r << 6) + ((cc ^ (r & 7)) << 3);
        bF[n] = *(const short8*)&lds[8192 + off];
      }
#pragma unroll
      for (int m = 0; m < 2; ++m)
#pragma unroll
        for (int n = 0; n < 4; ++n) {
          accC[m][n] = __builtin_amdgcn_mfma_f32_16x16x32_bf16(aC[m], bF[n], accC[m][n], 0, 0, 0);
          accS[m][n] = __builtin_amdgcn_mfma_f32_16x16x32_bf16(aS[m], bF[n], accS[m][n], 0, 0, 0);
        }
    }
  }

  // epilogue: bf16 partial write (16 consecutive lanes -> 32B contiguous)
#pragma unroll
  for (int m = 0; m < 2; ++m) {
    const int row = k0 + wrow + m * 16 + (lane >> 4) * 4;
#pragma unroll
    for (int n = 0; n < 4; ++n) {
      const int col = j0 + wcol + n * 16 + (lane & 15);
      const size_t base = (size_t)row * NCOL + col;
#pragma unroll
      for (int r = 0; r < 4; ++r) {
        pC[base + (size_t)r * NCOL] = cvt_bf16(accC[m][n][r]);
        pS[base + (size_t)r * NCOL] = cvt_bf16(accS[m][n][r]);
      }
    }
  }

  // ---- last-arriver combine ----
  __threadfence();                       // release: partials visible device-wide
  __shared__ int ticket;
  if (tid == 0) ticket = atomicAdd(&cnt[grp], 1);
  __syncthreads();
  if (ticket != 3) return;               // block-uniform exit
  __threadfence();                       // acquire: see all 4 sides' partials

  const int jq0 = j0 >> 2;               // 32 quads in this j-tile
  for (int item = tid; item < 64 * 32; item += 256)
    combine_item(k0 + (item >> 5), jq0 + (item & 31), pC4, pS4, Tbuf, outR, outI);
  if (kt == 3)
    for (int item = tid; item < 32; item += 256)
      combine_item(256, jq0 + item, pC4, pS4, Tbuf, outR, outI);
}

// ==================== fallback: R4 full-K path (proven, small ws) ====================

__global__ __launch_bounds__(256) void conv_w_kernel(const float* __restrict__ wsin,
                                                     const float* __restrict__ wcos,
                                                     short* __restrict__ wc,
                                                     short* __restrict__ ws) {
  const int row = blockIdx.x;
  const int c = threadIdx.x * 8;
  const float* src = (blockIdx.y ? wsin : wcos) + (size_t)row * NFFT + c;
  short* dst = (blockIdx.y ? ws : wc) + (size_t)row * NFFT + c;
  f32x4 a = *(const f32x4*)src;
  f32x4 b = *(const f32x4*)(src + 4);
  short8 o;
#pragma unroll
  for (int j = 0; j < 4; ++j) { o[j] = cvt_bf16(a[j]); o[4 + j] = cvt_bf16(b[j]); }
  *(short8*)dst = o;
}

__global__ __launch_bounds__(256) void conv_frames_kernel(const float* __restrict__ x,
                                                          short* __restrict__ fr) {
  const int j = blockIdx.x;
  const int b = j / NTP;
  const int t = j - b * NTP;
  const int c = threadIdx.x * 8;
  short8 o;
  if (t >= NT) {
#pragma unroll
    for (int k = 0; k < 8; ++k) o[k] = 0;
  } else {
    const float* xb = x + (size_t)b * XLEN;
    const int base = t * 512 + c - 1024;
    float v[8];
    if (base >= 0 && base + 7 < XLEN) {
      *(f32x4*)(v)     = *(const f32x4*)(xb + base);
      *(f32x4*)(v + 4) = *(const f32x4*)(xb + base + 4);
    } else {
#pragma unroll
      for (int k = 0; k < 8; ++k) {
        int m = base + k;
        m = (m < 0) ? -m : m;
        m = (m >= XLEN) ? (2 * XLEN - 2 - m) : m;
        v[k] = xb[m];
      }
    }
#pragma unroll
    for (int k = 0; k < 8; ++k) o[k] = cvt_bf16(v[k]);
  }
  *(short8*)&fr[(size_t)j * NFFT + c] = o;
}

__global__ __launch_bounds__(256, 3) void dft_gemm_r4(
    const short* __restrict__ wc_bf,
    const short* __restrict__ ws_bf,
    const short* __restrict__ fr_bf,
    float* __restrict__ outR,
    float* __restrict__ outI) {
  __shared__ short lds[16384];

  const int tid  = threadIdx.x;
  const int lane = tid & 63;
  const int wid  = tid >> 6;

  const int o   = blockIdx.x;
  const int xcd = o & 7;
  const int wg  = ((xcd < 1) ? xcd * 71 : 71 + (xcd - 1) * 70) + (o >> 3);
  const int k0  = (wg % 17) * 64;
  const int j0  = (wg / 17) * 128;

  const int wrow = (wid >> 1) * 32;
  const int wcol = (wid & 1) * 64;

  f32x4 accR[2][4], accI[2][4];
#pragma unroll
  for (int m = 0; m < 2; ++m)
#pragma unroll
    for (int n = 0; n < 4; ++n) { accR[m][n] = (f32x4)0.0f; accI[m][n] = (f32x4)0.0f; }

  const int fr_r = lane & 15;
  const int srow = lane >> 3;
  const int scol = ((lane & 7) ^ srow) * 8;

  auto stage = [&](int n0) {
#pragma unroll
    for (int i = 0; i < 8; ++i) {
      const int q = wid * 8 + i;
      const short* src;
      int dst;
      if (q < 8) {
        src = wc_bf + (size_t)(k0 + q * 8 + srow) * NFFT + n0 + scol;
        dst = q * 512;
      } else if (q < 16) {
        src = ws_bf + (size_t)(k0 + (q - 8) * 8 + srow) * NFFT + n0 + scol;
        dst = 4096 + (q - 8) * 512;
      } else {
        src = fr_bf + (size_t)(j0 + (q - 16) * 8 + srow) * NFFT + n0 + scol;
        dst = 8192 + (q - 16) * 512;
      }
      gload16(src, &lds[dst]);
    }
  };

  for (int t = 0; t < 32; ++t) {
    if (t) __syncthreads();
    stage(t * 64);
    __syncthreads();
#pragma unroll
    for (int ks = 0; ks < 2; ++ks) {
      const int cc = ks * 4 + (lane >> 4);
      short8 a_c[2], a_s[2], b_f[4];
#pragma unroll
      for (int m = 0; m < 2; ++m) {
        const int r = wrow + m * 16 + fr_r;
        const int off = (r << 6) + ((cc ^ (r & 7)) << 3);
        a_c[m] = *(const short8*)&lds[off];
        a_s[m] = *(const short8*)&lds[4096 + off];
      }
#pragma unroll
      for (int n = 0; n < 4; ++n) {
        const int r = wcol + n * 16 + fr_r;
        const int off = (r << 6) + ((cc ^ (r & 7)) << 3);
        b_f[n] = *(const short8*)&lds[8192 + off];
      }
#pragma unroll
      for (int m = 0; m < 2; ++m)
#pragma unroll
        for (int n = 0; n < 4; ++n) {
          accR[m][n] = __builtin_amdgcn_mfma_f32_16x16x32_bf16(a_c[m], b_f[n], accR[m][n], 0, 0, 0);
          accI[m][n] = __builtin_amdgcn_mfma_f32_16x16x32_bf16(a_s[m], b_f[n], accI[m][n], 0, 0, 0);
        }
    }
  }

#pragma unroll
  for (int m = 0; m < 2; ++m) {
    const int k = k0 + wrow + m * 16 + (lane >> 4) * 4;
#pragma unroll
    for (int n = 0; n < 4; ++n) {
      const int j = j0 + wcol + n * 16 + (lane & 15);
      const int b = j / NTP;
      const int t = j - b * NTP;
      if (t < NT) {
        const size_t base = (size_t)b * OUTKT + (size_t)k * NT + t;
#pragma unroll
        for (int r = 0; r < 4; ++r) {
          const int kk = k + r;
          const float vr = accR[m][n][r];
          const float vi = accI[m][n][r];
          outR[base + (size_t)r * NT] = vr;
          outI[base + (size_t)r * NT] = -vi;
          if (kk >= 1 && kk <= 960) {
            const size_t mb = (size_t)b * OUTKT + (size_t)(2048 - kk) * NT + t;
            outR[mb] = vr;
            outI[mb] = vi;
          }
        }
      }
    }
  }
}

// ==================== host ====================

extern "C" void kernel_launch(void* const* d_in, const int* in_sizes, int n_in,
                              void* d_out, int out_size, void* d_ws, size_t ws_size,
                              hipStream_t stream) {
  const float* x    = (const float*)d_in[0];
  const float* wsin = (const float*)d_in[1];
  const float* wcos = (const float*)d_in[2];
  float* outR = (float*)d_out;
  float* outI = outR + (size_t)NB * OUTKT;

  // workspace: 8 weight mats + 4 frame mats + 8 bf16 partials + T + counters
  const size_t need4 = (8 * WSTR + 4 * FSTR + 8 * PSTR) * sizeof(short)
                     + (size_t)NCOL * 4 * sizeof(float) + NGRP * sizeof(int);

  if (ws_size >= need4) {
    short* wc4 = (short*)d_ws;                    // [4][256][512]
    short* ws4 = wc4 + 4 * WSTR;                  // [4][256][512]
    short* fr4 = ws4 + 4 * WSTR;                  // [4][4224][512]
    short* pC4 = fr4 + 4 * FSTR;                  // [4][256][4224] bf16
    short* pS4 = pC4 + 4 * PSTR;                  // [4][256][4224] bf16
    float* Tbuf = (float*)(pS4 + 4 * PSTR);       // [4224][4] f32
    int*   cnt  = (int*)(Tbuf + (size_t)NCOL * 4);// [132]

    conv_prep4<<<PROW + NCOL, 256, 0, stream>>>(x, wsin, wcos, wc4, ws4, fr4, Tbuf, cnt);
    dft_gemm_split4<<<NWG4, 256, 0, stream>>>(wc4, ws4, fr4, pC4, pS4, Tbuf, cnt, outR, outI);
  } else {
    // R4 full-K fallback (needs ~26.2 MB)
    short* wc_bf = (short*)d_ws;
    short* ws_bf = wc_bf + (size_t)NK * NFFT;
    short* fr_bf = ws_bf + (size_t)NK * NFFT;
    conv_w_kernel<<<dim3(NK, 2), 256, 0, stream>>>(wsin, wcos, wc_bf, ws_bf);
    conv_frames_kernel<<<NCOL, 256, 0, stream>>>(x, fr_bf);
    dft_gemm_r4<<<561, 256, 0, stream>>>(wc_bf, ws_bf, fr_bf, outR, outI);
  }
}

// Round 20
// 56.999 us; speedup vs baseline: 3.9730x; 3.9730x over previous
//
#include <hip/hip_runtime.h>
#include <hip/hip_bf16.h>
#include <stdint.h>

#define XLEN   262144
#define NT     513
#define NTP    528               // padded frames per batch (8*528 = 4224)
#define NB     8
#define NCOL   (NB * NTP)        // 4224 fused columns
#define NKC4   320               // padded computed k rows (valid 0..256), 5 tiles
#define KQ     512               // quarter transform length (radix-4)
#define NK     1088              // fallback path: direct rows
#define NFFT   2048
#define OUTKT  (2048 * NT)
#define WSTR   ((size_t)NKC4 * KQ)   // 163,840 shorts per weight mat
#define FSTR   ((size_t)NCOL * KQ)   // 2,162,688 shorts per frame mat
#define PSTR   ((size_t)NKC4 * NCOL) // 1,351,680 elements per partial (bf16)

typedef __attribute__((ext_vector_type(8))) short short8;
typedef __attribute__((ext_vector_type(4))) short short4v;
typedef __attribute__((ext_vector_type(2))) short short2v;
typedef __attribute__((ext_vector_type(4))) float f32x4;

__device__ __forceinline__ short cvt_bf16(float f) {
  return __builtin_bit_cast(short, (__bf16)f);
}

__device__ __forceinline__ f32x4 bf4_to_f32(short4v v) {
  f32x4 o;
#pragma unroll
  for (int e = 0; e < 4; ++e) {
    uint32_t u = ((uint32_t)(uint16_t)v[e]) << 16;
    o[e] = __builtin_bit_cast(float, u);
  }
  return o;
}

__device__ __forceinline__ void gload16(const short* g, const short* l) {
  __builtin_amdgcn_global_load_lds(
      (const __attribute__((address_space(1))) void*)g,
      (__attribute__((address_space(3))) void*)l, 16, 0, 0);
}

// ==================== radix-4 split path (benched 57.09 us) ====================

// ---- fused prep: blocks [0,NKC4) split weights; [NKC4, NKC4+NCOL) split frames.
__global__ __launch_bounds__(256) void conv_prep4(
    const float* __restrict__ x,
    const float* __restrict__ wsin, const float* __restrict__ wcos,
    short* __restrict__ wc4, short* __restrict__ ws4,
    short* __restrict__ fr4) {
  const int n0 = threadIdx.x * 8;
  const int m0 = n0 >> 2;
  if (blockIdx.x < NKC4) {
    const int row = blockIdx.x;           // 0..319
    short2v c[4], s[4];
    if (row <= 256) {
      const float* pc = wcos + (size_t)row * NFFT + n0;
      const float* ps = wsin + (size_t)row * NFFT + n0;
      f32x4 c0 = *(const f32x4*)pc, c1 = *(const f32x4*)(pc + 4);
      f32x4 s0 = *(const f32x4*)ps, s1 = *(const f32x4*)(ps + 4);
#pragma unroll
      for (int r = 0; r < 4; ++r) {
        c[r][0] = cvt_bf16(c0[r]); c[r][1] = cvt_bf16(c1[r]);
        s[r][0] = cvt_bf16(s0[r]); s[r][1] = cvt_bf16(s1[r]);
      }
    } else {
#pragma unroll
      for (int r = 0; r < 4; ++r) { c[r][0] = 0; c[r][1] = 0; s[r][0] = 0; s[r][1] = 0; }
    }
    const size_t o = (size_t)row * KQ + m0;
#pragma unroll
    for (int r = 0; r < 4; ++r) {
      *(short2v*)&wc4[r * WSTR + o] = c[r];
      *(short2v*)&ws4[r * WSTR + o] = s[r];
    }
  } else {
    const int j = blockIdx.x - NKC4;      // 0..4223
    const int b = j / NTP;
    const int t = j - b * NTP;
    short2v v[4];
    if (t < NT) {
      const float* xb = x + (size_t)b * XLEN;
      const int q0 = t * 512 + n0 - 1024;
      float f[8];
      if (q0 >= 0 && q0 + 7 < XLEN) {
        *(f32x4*)(f)     = *(const f32x4*)(xb + q0);
        *(f32x4*)(f + 4) = *(const f32x4*)(xb + q0 + 4);
      } else {
#pragma unroll
        for (int e = 0; e < 8; ++e) {
          int mm = q0 + e;
          mm = (mm < 0) ? -mm : mm;
          mm = (mm >= XLEN) ? (2 * XLEN - 2 - mm) : mm;
          f[e] = xb[mm];
        }
      }
#pragma unroll
      for (int r = 0; r < 4; ++r) { v[r][0] = cvt_bf16(f[r]); v[r][1] = cvt_bf16(f[4 + r]); }
    } else {
#pragma unroll
      for (int r = 0; r < 4; ++r) { v[r][0] = 0; v[r][1] = 0; }
    }
#pragma unroll
    for (int r = 0; r < 4; ++r)
      *(short2v*)&fr4[r * FSTR + (size_t)j * KQ + m0] = v[r];
  }
}

// ---- split GEMM: K=512, one residue side per block ----
// BM=64, BN=128, BK=64; 4 waves 2x2, each 32x64 per matrix; per substep
// 8 ds_read_b128 : 16 MFMA. LDS single 32 KiB [A_c 64x64 | A_s 64x64 | B 128x64],
// (row&7) 16B-chunk XOR swizzle on global source + ds_read (rule #21).
// Partials written as bf16 (R14 error budget).
__global__ __launch_bounds__(256, 3) void dft_gemm_split4(
    const short* __restrict__ wc4, const short* __restrict__ ws4,
    const short* __restrict__ fr4,
    short* __restrict__ pC4, short* __restrict__ pS4) {
  __shared__ short lds[16384];  // 32 KiB

  const int tid  = threadIdx.x;
  const int lane = tid & 63;
  const int wid  = tid >> 6;

  // bijective XCD swizzle (m204): nwg=660, q=82, r=4.
  const int o   = blockIdx.x;
  const int xcd = o & 7;
  const int i   = o >> 3;
  const int wg  = ((xcd < 4) ? xcd * 83 : 332 + (xcd - 4) * 82) + i;
  const int side = wg / 165;        // residue r = 0..3
  const int w    = wg - side * 165;
  const int k0   = (w % 5) * 64;
  const int j0   = (w / 5) * 128;

  const short* Ac = wc4 + side * WSTR;
  const short* As = ws4 + side * WSTR;
  const short* Bf = fr4 + side * FSTR;
  short* pC = pC4 + side * PSTR;
  short* pS = pS4 + side * PSTR;

  const int wrow = (wid >> 1) * 32;
  const int wcol = (wid & 1) * 64;

  f32x4 accC[2][4], accS[2][4];
#pragma unroll
  for (int m = 0; m < 2; ++m)
#pragma unroll
    for (int n = 0; n < 4; ++n) { accC[m][n] = (f32x4)0.0f; accS[m][n] = (f32x4)0.0f; }

  const int fr_r = lane & 15;
  const int srow = lane >> 3;
  const int scol = ((lane & 7) ^ srow) * 8;

  // buffer = 32 chunks of (8 rows x 64 shorts); 8 per wave
  auto stage = [&](int n0) {
#pragma unroll
    for (int i2 = 0; i2 < 8; ++i2) {
      const int q = wid * 8 + i2;  // wave-uniform
      const short* src;
      int dst;
      if (q < 8) {
        src = Ac + (size_t)(k0 + q * 8 + srow) * KQ + n0 + scol;
        dst = q * 512;
      } else if (q < 16) {
        src = As + (size_t)(k0 + (q - 8) * 8 + srow) * KQ + n0 + scol;
        dst = 4096 + (q - 8) * 512;
      } else {
        src = Bf + (size_t)(j0 + (q - 16) * 8 + srow) * KQ + n0 + scol;
        dst = 8192 + (q - 16) * 512;
      }
      gload16(src, &lds[dst]);
    }
  };

  for (int ts = 0; ts < 8; ++ts) {
    if (ts) __syncthreads();
    stage(ts * 64);
    __syncthreads();
#pragma unroll
    for (int ks = 0; ks < 2; ++ks) {
      const int cc = ks * 4 + (lane >> 4);
      short8 aC[2], aS[2], bF[4];
#pragma unroll
      for (int m = 0; m < 2; ++m) {
        const int r = wrow + m * 16 + fr_r;
        const int off = (r << 6) + ((cc ^ (r & 7)) << 3);
        aC[m] = *(const short8*)&lds[off];
        aS[m] = *(const short8*)&lds[4096 + off];
      }
#pragma unroll
      for (int n = 0; n < 4; ++n) {
        const int r = wcol + n * 16 + fr_r;
        const int off = (r << 6) + ((cc ^ (r & 7)) << 3);
        bF[n] = *(const short8*)&lds[8192 + off];
      }
#pragma unroll
      for (int m = 0; m < 2; ++m)
#pragma unroll
        for (int n = 0; n < 4; ++n) {
          accC[m][n] = __builtin_amdgcn_mfma_f32_16x16x32_bf16(aC[m], bF[n], accC[m][n], 0, 0, 0);
          accS[m][n] = __builtin_amdgcn_mfma_f32_16x16x32_bf16(aS[m], bF[n], accS[m][n], 0, 0, 0);
        }
    }
  }

  // epilogue: bf16 partial write (16 consecutive lanes -> 32B contiguous)
#pragma unroll
  for (int m = 0; m < 2; ++m) {
    const int row = k0 + wrow + m * 16 + (lane >> 4) * 4;
#pragma unroll
    for (int n = 0; n < 4; ++n) {
      const int col = j0 + wcol + n * 16 + (lane & 15);
      const size_t base = (size_t)row * NCOL + col;
#pragma unroll
      for (int r = 0; r < 4; ++r) {
        pC[base + (size_t)r * NCOL] = cvt_bf16(accC[m][n][r]);
        pS[base + (size_t)r * NCOL] = cvt_bf16(accS[m][n][r]);
      }
    }
  }
}

// ---- combine: radix-4 butterfly + Hermitian mirrors (bf16 partials in) ----
// k in [0,256]. Direct rows d = 512*jj + k (always);
// mirror rows 2048 - d = 512*(4-jj) - k only for 1<=k<=255 (conj: outI flips).
// outR[row]=C_row, outI[row]=-S_row; mirrors: outR=C, outI=+S.
__global__ __launch_bounds__(256) void combine4_kernel(
    const short* __restrict__ pC4, const short* __restrict__ pS4,
    float* __restrict__ outR, float* __restrict__ outI) {
  const int k  = blockIdx.y;                       // 0..256
  const int jq = blockIdx.x * 256 + threadIdx.x;   // quad index
  if (jq >= NCOL / 4) return;
  const int j = jq * 4;
  const int b = j / NTP;
  const int t = j - b * NTP;                       // NTP%4==0 -> same b for all 4
  const size_t pb = (size_t)k * NCOL + j;
  f32x4 C[4], S[4];
#pragma unroll
  for (int r = 0; r < 4; ++r) {
    C[r] = bf4_to_f32(*(const short4v*)&pC4[r * PSTR + pb]);
    S[r] = bf4_to_f32(*(const short4v*)&pS4[r * PSTR + pb]);
  }
  const f32x4 CA = C[0] + C[2], CB = C[1] + C[3];
  const f32x4 CmA = C[0] - C[2], CmB = C[1] - C[3];
  const f32x4 SA = S[0] + S[2], SB = S[1] + S[3];
  const f32x4 SmA = S[0] - S[2], SmB = S[1] - S[3];

  f32x4 Cw[4], Sw[4];
  Cw[0] = CA + CB;   Sw[0] = SA + SB;    // row k
  Cw[1] = CmA - SmB; Sw[1] = SmA + CmB;  // row 512+k
  Cw[2] = CA - CB;   Sw[2] = SA - SB;    // row 1024+k
  Cw[3] = CmA + SmB; Sw[3] = SmA - CmB;  // row 1536+k

  const size_t ob = (size_t)b * OUTKT + t;
  const bool mir = (k >= 1) && (k <= 255);
#pragma unroll
  for (int jj = 0; jj < 4; ++jj) {
    const int rowD = 512 * jj + k;
    float* rD = outR + ob + (size_t)rowD * NT;
    float* iD = outI + ob + (size_t)rowD * NT;
    const int rowM = 512 * (4 - jj) - k;  // 2048-d: 2048-k,1536-k,1024-k,512-k
    float* rM = outR + ob + (size_t)rowM * NT;
    float* iM = outI + ob + (size_t)rowM * NT;
#pragma unroll
    for (int e = 0; e < 4; ++e) {
      if (t + e < NT) {
        rD[e] = Cw[jj][e];
        iD[e] = -Sw[jj][e];
        if (mir) { rM[e] = Cw[jj][e]; iM[e] = Sw[jj][e]; }
      }
    }
  }
}

// ==================== fallback: R4 full-K path (proven, small ws) ====================

__global__ __launch_bounds__(256) void conv_w_kernel(const float* __restrict__ wsin,
                                                     const float* __restrict__ wcos,
                                                     short* __restrict__ wc,
                                                     short* __restrict__ ws) {
  const int row = blockIdx.x;
  const int c = threadIdx.x * 8;
  const float* src = (blockIdx.y ? wsin : wcos) + (size_t)row * NFFT + c;
  short* dst = (blockIdx.y ? ws : wc) + (size_t)row * NFFT + c;
  f32x4 a = *(const f32x4*)src;
  f32x4 b = *(const f32x4*)(src + 4);
  short8 o;
#pragma unroll
  for (int j = 0; j < 4; ++j) { o[j] = cvt_bf16(a[j]); o[4 + j] = cvt_bf16(b[j]); }
  *(short8*)dst = o;
}

__global__ __launch_bounds__(256) void conv_frames_kernel(const float* __restrict__ x,
                                                          short* __restrict__ fr) {
  const int j = blockIdx.x;
  const int b = j / NTP;
  const int t = j - b * NTP;
  const int c = threadIdx.x * 8;
  short8 o;
  if (t >= NT) {
#pragma unroll
    for (int k = 0; k < 8; ++k) o[k] = 0;
  } else {
    const float* xb = x + (size_t)b * XLEN;
    const int base = t * 512 + c - 1024;
    float v[8];
    if (base >= 0 && base + 7 < XLEN) {
      *(f32x4*)(v)     = *(const f32x4*)(xb + base);
      *(f32x4*)(v + 4) = *(const f32x4*)(xb + base + 4);
    } else {
#pragma unroll
      for (int k = 0; k < 8; ++k) {
        int m = base + k;
        m = (m < 0) ? -m : m;
        m = (m >= XLEN) ? (2 * XLEN - 2 - m) : m;
        v[k] = xb[m];
      }
    }
#pragma unroll
    for (int k = 0; k < 8; ++k) o[k] = cvt_bf16(v[k]);
  }
  *(short8*)&fr[(size_t)j * NFFT + c] = o;
}

__global__ __launch_bounds__(256, 3) void dft_gemm_r4(
    const short* __restrict__ wc_bf,
    const short* __restrict__ ws_bf,
    const short* __restrict__ fr_bf,
    float* __restrict__ outR,
    float* __restrict__ outI) {
  __shared__ short lds[16384];

  const int tid  = threadIdx.x;
  const int lane = tid & 63;
  const int wid  = tid >> 6;

  const int o   = blockIdx.x;
  const int xcd = o & 7;
  const int wg  = ((xcd < 1) ? xcd * 71 : 71 + (xcd - 1) * 70) + (o >> 3);
  const int k0  = (wg % 17) * 64;
  const int j0  = (wg / 17) * 128;

  const int wrow = (wid >> 1) * 32;
  const int wcol = (wid & 1) * 64;

  f32x4 accR[2][4], accI[2][4];
#pragma unroll
  for (int m = 0; m < 2; ++m)
#pragma unroll
    for (int n = 0; n < 4; ++n) { accR[m][n] = (f32x4)0.0f; accI[m][n] = (f32x4)0.0f; }

  const int fr_r = lane & 15;
  const int srow = lane >> 3;
  const int scol = ((lane & 7) ^ srow) * 8;

  auto stage = [&](int n0) {
#pragma unroll
    for (int i = 0; i < 8; ++i) {
      const int q = wid * 8 + i;
      const short* src;
      int dst;
      if (q < 8) {
        src = wc_bf + (size_t)(k0 + q * 8 + srow) * NFFT + n0 + scol;
        dst = q * 512;
      } else if (q < 16) {
        src = ws_bf + (size_t)(k0 + (q - 8) * 8 + srow) * NFFT + n0 + scol;
        dst = 4096 + (q - 8) * 512;
      } else {
        src = fr_bf + (size_t)(j0 + (q - 16) * 8 + srow) * NFFT + n0 + scol;
        dst = 8192 + (q - 16) * 512;
      }
      gload16(src, &lds[dst]);
    }
  };

  for (int t = 0; t < 32; ++t) {
    if (t) __syncthreads();
    stage(t * 64);
    __syncthreads();
#pragma unroll
    for (int ks = 0; ks < 2; ++ks) {
      const int cc = ks * 4 + (lane >> 4);
      short8 a_c[2], a_s[2], b_f[4];
#pragma unroll
      for (int m = 0; m < 2; ++m) {
        const int r = wrow + m * 16 + fr_r;
        const int off = (r << 6) + ((cc ^ (r & 7)) << 3);
        a_c[m] = *(const short8*)&lds[off];
        a_s[m] = *(const short8*)&lds[4096 + off];
      }
#pragma unroll
      for (int n = 0; n < 4; ++n) {
        const int r = wcol + n * 16 + fr_r;
        const int off = (r << 6) + ((cc ^ (r & 7)) << 3);
        b_f[n] = *(const short8*)&lds[8192 + off];
      }
#pragma unroll
      for (int m = 0; m < 2; ++m)
#pragma unroll
        for (int n = 0; n < 4; ++n) {
          accR[m][n] = __builtin_amdgcn_mfma_f32_16x16x32_bf16(a_c[m], b_f[n], accR[m][n], 0, 0, 0);
          accI[m][n] = __builtin_amdgcn_mfma_f32_16x16x32_bf16(a_s[m], b_f[n], accI[m][n], 0, 0, 0);
        }
    }
  }

#pragma unroll
  for (int m = 0; m < 2; ++m) {
    const int k = k0 + wrow + m * 16 + (lane >> 4) * 4;
#pragma unroll
    for (int n = 0; n < 4; ++n) {
      const int j = j0 + wcol + n * 16 + (lane & 15);
      const int b = j / NTP;
      const int t = j - b * NTP;
      if (t < NT) {
        const size_t base = (size_t)b * OUTKT + (size_t)k * NT + t;
#pragma unroll
        for (int r = 0; r < 4; ++r) {
          const int kk = k + r;
          const float vr = accR[m][n][r];
          const float vi = accI[m][n][r];
          outR[base + (size_t)r * NT] = vr;
          outI[base + (size_t)r * NT] = -vi;
          if (kk >= 1 && kk <= 960) {
            const size_t mb = (size_t)b * OUTKT + (size_t)(2048 - kk) * NT + t;
            outR[mb] = vr;
            outI[mb] = vi;
          }
        }
      }
    }
  }
}

// ==================== host ====================

extern "C" void kernel_launch(void* const* d_in, const int* in_sizes, int n_in,
                              void* d_out, int out_size, void* d_ws, size_t ws_size,
                              hipStream_t stream) {
  const float* x    = (const float*)d_in[0];
  const float* wsin = (const float*)d_in[1];
  const float* wcos = (const float*)d_in[2];
  float* outR = (float*)d_out;
  float* outI = outR + (size_t)NB * OUTKT;

  // radix-4 workspace: 8 weight mats + 4 frame mats + 8 bf16 partials (~41.6 MB)
  const size_t need4 = (8 * WSTR + 4 * FSTR + 8 * PSTR) * sizeof(short);

  if (ws_size >= need4) {
    short* wc4 = (short*)d_ws;                    // [4][320][512]
    short* ws4 = wc4 + 4 * WSTR;                  // [4][320][512]
    short* fr4 = ws4 + 4 * WSTR;                  // [4][4224][512]
    short* pC4 = fr4 + 4 * FSTR;                  // [4][320][4224] bf16
    short* pS4 = pC4 + 4 * PSTR;                  // [4][320][4224] bf16

    conv_prep4<<<NKC4 + NCOL, 256, 0, stream>>>(x, wsin, wcos, wc4, ws4, fr4);
    dft_gemm_split4<<<660, 256, 0, stream>>>(wc4, ws4, fr4, pC4, pS4);
    combine4_kernel<<<dim3(5, 257), 256, 0, stream>>>(pC4, pS4, outR, outI);
  } else {
    // R4 full-K fallback (needs ~26.2 MB)
    short* wc_bf = (short*)d_ws;
    short* ws_bf = wc_bf + (size_t)NK * NFFT;
    short* fr_bf = ws_bf + (size_t)NK * NFFT;
    conv_w_kernel<<<dim3(NK, 2), 256, 0, stream>>>(wsin, wcos, wc_bf, ws_bf);
    conv_frames_kernel<<<NCOL, 256, 0, stream>>>(x, fr_bf);
    dft_gemm_r4<<<561, 256, 0, stream>>>(wc_bf, ws_bf, fr_bf, outR, outI);
  }
}